// Round 3
// baseline (19632.486 us; speedup 1.0000x reference)
//
#include <hip/hip_runtime.h>
#include <math.h>

// Problem constants (fixed by setup_inputs)
constexpr int U      = 128;   // UNITS
constexpr int G4     = 512;   // 4*U gate width
constexpr int NC     = 10;    // classes
constexpr int TSTEPS = 1000;
constexpr int BATCH  = 256;

__device__ __forceinline__ float sigm(float x) {
    return 1.0f / (1.0f + __expf(-x));
}

// matches jnp.mod (floor-mod) semantics: fmod exact, then sign-adjust
__device__ __forceinline__ float tgate(float t, float tau, float s) {
    float r = fmodf(t - s, tau);
    if (r < 0.0f) r += tau;
    float phi = r / tau;
    if (phi < 0.025f) return 40.0f * phi;        // 2*phi/R_ON
    if (phi < 0.05f)  return 2.0f - 40.0f * phi; // 2 - 2*phi/R_ON
    return 0.001f * phi;                          // ALPHA*phi
}

__device__ __forceinline__ float4 f4ma(float s, float4 a, float4 acc) {
    acc.x += s * a.x; acc.y += s * a.y; acc.z += s * a.z; acc.w += s * a.w;
    return acc;
}

// One workgroup per batch element, 512 threads = 8 waves.
// Thread tid: g = tid>>7 (K-quarter, wave-pair uniform), l = tid&127,
// owns output columns 4l..4l+3 and K-range [32g, 32g+32).
// Register-cached: full Wh0 slice (128 VGPR) + Wx1 rows kbase..kbase+7 (32 VGPR).
// __launch_bounds__(512, 1) => VGPR cap 256, NO spill (round-2 lesson: the
// default heuristic caps at 128 and spills the weight cache to scratch).
__global__ __launch_bounds__(512, 1) void plstm_fused(
    const float* __restrict__ inputs,  // [B,T,3]
    const float* __restrict__ times,   // [B,T]
    const float* __restrict__ Wx0,     // [3,512]
    const float* __restrict__ Wh0,     // [128,512]
    const float* __restrict__ b0,      // [512]
    const float* __restrict__ tau0,    // [128]
    const float* __restrict__ s0,      // [128]
    const float* __restrict__ Wx1,     // [128,512]
    const float* __restrict__ Wh1,     // [128,512]
    const float* __restrict__ b1,      // [512]
    const float* __restrict__ tau1,    // [128]
    const float* __restrict__ s1,      // [128]
    const float* __restrict__ gamma_,  // [128]
    const float* __restrict__ beta_,   // [128]
    const float* __restrict__ Wfc,     // [128,10]
    const float* __restrict__ bfc,     // [10]
    float* __restrict__ out)           // [B,T,10]
{
    const int b   = blockIdx.x;
    const int tid = threadIdx.x;
    const int g   = tid >> 7;        // 0..3  (wave-pair uniform)
    const int l   = tid & 127;       // 0..127
    const int kbase = 32 * g;
    const int cbase = 4 * l;

    __shared__ __align__(16) float h0s[U];
    __shared__ __align__(16) float h1s[U];
    __shared__ __align__(16) float hns[U];
    __shared__ __align__(16) float zs4[4 * G4];   // split-K partials [g][col]
    __shared__ __align__(16) float xsL[3 * TSTEPS];
    __shared__ __align__(16) float tsL[TSTEPS];
    __shared__ float WfcL[U * NC];
    __shared__ float bfcL[NC];
    __shared__ float psum[2], psq[2];             // LN partials per wave-half

    // ---- register-cached weights (loop-invariant) ----
    float4 wh0c[32];                 // full Wh0 slice: 128 VGPRs
    #pragma unroll
    for (int kk = 0; kk < 32; ++kk)
        wh0c[kk] = *reinterpret_cast<const float4*>(&Wh0[(kbase + kk) * G4 + cbase]);
    constexpr int WX1C = 8;          // cached Wx1 rows: 32 VGPRs
    float4 wx1c[WX1C];
    #pragma unroll
    for (int kk = 0; kk < WX1C; ++kk)
        wx1c[kk] = *reinterpret_cast<const float4*>(&Wx1[(kbase + kk) * G4 + cbase]);

    // g==0 threads fold bias + x@Wx0 into their partial (wave-uniform branch)
    float4 b0v = {0,0,0,0}, b1v = {0,0,0,0};
    float4 wx0a = {0,0,0,0}, wx0b = {0,0,0,0}, wx0c = {0,0,0,0};
    if (g == 0) {
        b0v  = *reinterpret_cast<const float4*>(&b0[cbase]);
        b1v  = *reinterpret_cast<const float4*>(&b1[cbase]);
        wx0a = *reinterpret_cast<const float4*>(&Wx0[cbase]);
        wx0b = *reinterpret_cast<const float4*>(&Wx0[G4 + cbase]);
        wx0c = *reinterpret_cast<const float4*>(&Wx0[2 * G4 + cbase]);
    }

    // per-unit state in registers (tid<128 owns unit tid)
    float tau0r = 0.f, s0r = 0.f, tau1r = 0.f, s1r = 0.f, gr = 0.f, br = 0.f;
    float c0r = 0.f, c1r = 0.f, h0r = 0.f, h1r = 0.f;
    if (tid < U) {
        tau0r = tau0[tid]; s0r = s0[tid];
        tau1r = tau1[tid]; s1r = s1[tid];
        gr = gamma_[tid];  br = beta_[tid];
        h0s[tid] = 0.0f;   h1s[tid] = 0.0f;
    }
    for (int i = tid; i < U * NC; i += 512) WfcL[i] = Wfc[i];
    if (tid < NC) bfcL[tid] = bfc[tid];

    // stage this block's inputs/times into LDS (coalesced, once)
    {
        const float* xp = inputs + (size_t)b * TSTEPS * 3;
        const float* tp = times  + (size_t)b * TSTEPS;
        for (int i = tid; i < 3 * TSTEPS; i += 512) xsL[i] = xp[i];
        for (int i = tid; i < TSTEPS; i += 512)     tsL[i] = tp[i];
    }
    __syncthreads();

    float* op = out + (size_t)b * TSTEPS * NC;

    const float* wx1p = Wx1 + kbase * G4 + cbase;
    const float* wh1p = Wh1 + kbase * G4 + cbase;

    for (int t = 0; t < TSTEPS; ++t) {
        const float x0 = xsL[3 * t + 0];   // wave-uniform -> LDS broadcast
        const float x1 = xsL[3 * t + 1];
        const float x2 = xsL[3 * t + 2];
        const float tv = tsL[t];

        // ---- phase 1: layer-0 partial (registers + LDS broadcast only)
        float4 acc = {0,0,0,0};
        if (g == 0) {
            acc = b0v;
            acc = f4ma(x0, wx0a, acc);
            acc = f4ma(x1, wx0b, acc);
            acc = f4ma(x2, wx0c, acc);
        }
        #pragma unroll
        for (int q = 0; q < 8; ++q) {
            const float4 h4 = *reinterpret_cast<const float4*>(&h0s[kbase + 4 * q]);
            acc = f4ma(h4.x, wh0c[4 * q + 0], acc);
            acc = f4ma(h4.y, wh0c[4 * q + 1], acc);
            acc = f4ma(h4.z, wh0c[4 * q + 2], acc);
            acc = f4ma(h4.w, wh0c[4 * q + 3], acc);
        }
        *reinterpret_cast<float4*>(&zs4[g * G4 + cbase]) = acc;
        __syncthreads();                                            // bar 1

        // ---- phase 2: layer-0 gates + state + LN partial sums (tid<128)
        if (tid < U) {
            float zi = 0.f, zf = 0.f, zg = 0.f, zo = 0.f;
            #pragma unroll
            for (int gg2 = 0; gg2 < 4; ++gg2) {
                zi += zs4[gg2 * G4 + tid];
                zf += zs4[gg2 * G4 + tid + U];
                zg += zs4[gg2 * G4 + tid + 2 * U];
                zo += zs4[gg2 * G4 + tid + 3 * U];
            }
            const float ig = sigm(zi);
            const float fg = sigm(zf);
            const float gv = tanhf(zg);
            const float og = sigm(zo);
            const float ch = fg * c0r + ig * gv;
            const float hh = og * tanhf(ch);
            const float k  = tgate(tv, tau0r, s0r);
            h0r = k * hh + (1.0f - k) * h0r;
            c0r = k * ch + (1.0f - k) * c0r;
            h0s[tid] = h0r;
            // one-pass LN partials within each 64-wide wave half
            float ssum = h0r;
            float qsum = h0r * h0r;
            #pragma unroll
            for (int off = 1; off < 64; off <<= 1) {
                ssum += __shfl_xor(ssum, off);
                qsum += __shfl_xor(qsum, off);
            }
            if ((tid & 63) == 0) {
                psum[tid >> 6] = ssum;
                psq[tid >> 6]  = qsum;
            }
        }
        __syncthreads();                                            // bar 2

        // ---- phase 3: LayerNorm apply (tid<128), stats from one-pass moments
        if (tid < U) {
            const float s_  = psum[0] + psum[1];
            const float q_  = psq[0] + psq[1];
            const float mu  = s_ * (1.0f / 128.0f);
            const float var = q_ * (1.0f / 128.0f) - mu * mu;
            const float rstd = rsqrtf(var + 1e-3f);
            hns[tid] = gr * (h0r - mu) * rstd + br;
        }
        __syncthreads();                                            // bar 3

        // ---- phase 4: layer-1 partial: hn@Wx1 + h1@Wh1 over K-quarter
        float4 acc1 = {0,0,0,0};
        if (g == 0) acc1 = b1v;
        #pragma unroll
        for (int q = 0; q < 8; ++q) {
            const float4 hn4 = *reinterpret_cast<const float4*>(&hns[kbase + 4 * q]);
            const float4 h14 = *reinterpret_cast<const float4*>(&h1s[kbase + 4 * q]);
            #pragma unroll
            for (int i = 0; i < 4; ++i) {
                const int kk = 4 * q + i;
                float4 wx;
                if (kk < WX1C) wx = wx1c[kk];   // compile-time after unroll
                else wx = *reinterpret_cast<const float4*>(&wx1p[kk * G4]);
                const float4 wh = *reinterpret_cast<const float4*>(&wh1p[kk * G4]);
                const float hnv = (i == 0) ? hn4.x : (i == 1) ? hn4.y : (i == 2) ? hn4.z : hn4.w;
                const float h1v = (i == 0) ? h14.x : (i == 1) ? h14.y : (i == 2) ? h14.z : h14.w;
                acc1 = f4ma(hnv, wx, acc1);
                acc1 = f4ma(h1v, wh, acc1);
            }
        }
        *reinterpret_cast<float4*>(&zs4[g * G4 + cbase]) = acc1;
        __syncthreads();                                            // bar 4

        // ---- phase 5: layer-1 gates + state update (tid<128)
        if (tid < U) {
            float zi = 0.f, zf = 0.f, zg = 0.f, zo = 0.f;
            #pragma unroll
            for (int gg2 = 0; gg2 < 4; ++gg2) {
                zi += zs4[gg2 * G4 + tid];
                zf += zs4[gg2 * G4 + tid + U];
                zg += zs4[gg2 * G4 + tid + 2 * U];
                zo += zs4[gg2 * G4 + tid + 3 * U];
            }
            const float ig = sigm(zi);
            const float fg = sigm(zf);
            const float gv = tanhf(zg);
            const float og = sigm(zo);
            const float ch = fg * c1r + ig * gv;
            const float hh = og * tanhf(ch);
            const float k  = tgate(tv, tau1r, s1r);
            h1r = k * hh + (1.0f - k) * h1r;
            c1r = k * ch + (1.0f - k) * c1r;
            h1s[tid] = h1r;
        }
        __syncthreads();                                            // bar 5

        // ---- phase 6: FC + softmax (wave 0)
        // Hazards: FC reads h1s/WfcL only; next-step zs4 store is ordered
        // after bar5 and gates' zs4 reads completed before bar5. h1s is next
        // written in next step's phase 5 (after bar4'). Safe without bar 6.
        if (tid < 64) {
            const float a  = h1s[tid];
            const float bv = h1s[tid + 64];
            float p[NC];
            #pragma unroll
            for (int c = 0; c < NC; ++c)
                p[c] = a * WfcL[tid * NC + c] + bv * WfcL[(tid + 64) * NC + c];
            #pragma unroll
            for (int off = 1; off < 64; off <<= 1) {
                #pragma unroll
                for (int c = 0; c < NC; ++c) p[c] += __shfl_xor(p[c], off);
            }
            float m = -1e30f;
            #pragma unroll
            for (int c = 0; c < NC; ++c) { p[c] += bfcL[c]; m = fmaxf(m, p[c]); }
            float ss = 0.0f;
            #pragma unroll
            for (int c = 0; c < NC; ++c) { p[c] = __expf(p[c] - m); ss += p[c]; }
            const float inv = 1.0f / ss;
            if (tid < NC) op[t * NC + tid] = p[tid] * inv;
        }
    }
}

extern "C" void kernel_launch(void* const* d_in, const int* in_sizes, int n_in,
                              void* d_out, int out_size, void* d_ws, size_t ws_size,
                              hipStream_t stream) {
    const float* inputs = (const float*)d_in[0];
    const float* times  = (const float*)d_in[1];
    const float* Wx0    = (const float*)d_in[2];
    const float* Wh0    = (const float*)d_in[3];
    const float* b0     = (const float*)d_in[4];
    const float* tau0   = (const float*)d_in[5];
    const float* s0     = (const float*)d_in[6];
    const float* Wx1    = (const float*)d_in[7];
    const float* Wh1    = (const float*)d_in[8];
    const float* b1     = (const float*)d_in[9];
    const float* tau1   = (const float*)d_in[10];
    const float* s1     = (const float*)d_in[11];
    const float* gamma_ = (const float*)d_in[12];
    const float* beta_  = (const float*)d_in[13];
    const float* Wfc    = (const float*)d_in[14];
    const float* bfc    = (const float*)d_in[15];
    float* out = (float*)d_out;

    dim3 grid(BATCH);
    dim3 block(512);
    hipLaunchKernelGGL(plstm_fused, grid, block, 0, stream,
                       inputs, times, Wx0, Wh0, b0, tau0, s0,
                       Wx1, Wh1, b1, tau1, s1, gamma_, beta_, Wfc, bfc, out);
}

// Round 4
// 16032.550 us; speedup vs baseline: 1.2245x; 1.2245x over previous
//
#include <hip/hip_runtime.h>
#include <math.h>

// Problem constants (fixed by setup_inputs)
constexpr int U      = 128;   // UNITS
constexpr int G4     = 512;   // 4*U gate width
constexpr int NC     = 10;    // classes
constexpr int TSTEPS = 1000;
constexpr int BATCH  = 256;
constexpr int LROWS  = 16;    // Wx1 rows per K-group cached in LDS (64 total = 128 KB)

__device__ __forceinline__ float sigm(float x) {
    return 1.0f / (1.0f + __expf(-x));
}

// matches jnp.mod (floor-mod) semantics: fmod exact, then sign-adjust
__device__ __forceinline__ float tgate(float t, float tau, float s) {
    float r = fmodf(t - s, tau);
    if (r < 0.0f) r += tau;
    float phi = r / tau;
    if (phi < 0.025f) return 40.0f * phi;        // 2*phi/R_ON
    if (phi < 0.05f)  return 2.0f - 40.0f * phi; // 2 - 2*phi/R_ON
    return 0.001f * phi;                          // ALPHA*phi
}

__device__ __forceinline__ float4 f4ma(float s, float4 a, float4 acc) {
    acc.x += s * a.x; acc.y += s * a.y; acc.z += s * a.z; acc.w += s * a.w;
    return acc;
}

// One workgroup per batch element, 512 threads = 8 waves, 1 block/CU.
// Thread tid: g = tid>>7 (K-quarter, wave-uniform), l = tid&127,
// owns output columns 4l..4l+3 and K-range [32g, 32g+32).
//
// Cache plan (round-2/3 lesson: the default allocator caps at 128 VGPR and
// spills; amdgpu_waves_per_eu(2,2) pins 2 waves/EU => 256-VGPR budget):
//   registers: full Wh0 slice        (32 float4 = 128 VGPR, cannot spill now)
//   LDS:       Wx1 rows kbase..+15   (128 KB, allocator-proof)
//   L2 stream: Wx1 rows kbase+16..31 + full Wh1 slice = 384 KB/block/step
__global__ __attribute__((amdgpu_flat_work_group_size(512, 512),
                          amdgpu_waves_per_eu(2, 2)))
void plstm_fused(
    const float* __restrict__ inputs,  // [B,T,3]
    const float* __restrict__ times,   // [B,T]
    const float* __restrict__ Wx0,     // [3,512]
    const float* __restrict__ Wh0,     // [128,512]
    const float* __restrict__ b0,      // [512]
    const float* __restrict__ tau0,    // [128]
    const float* __restrict__ s0,      // [128]
    const float* __restrict__ Wx1,     // [128,512]
    const float* __restrict__ Wh1,     // [128,512]
    const float* __restrict__ b1,      // [512]
    const float* __restrict__ tau1,    // [128]
    const float* __restrict__ s1,      // [128]
    const float* __restrict__ gamma_,  // [128]
    const float* __restrict__ beta_,   // [128]
    const float* __restrict__ Wfc,     // [128,10]
    const float* __restrict__ bfc,     // [10]
    float* __restrict__ out)           // [B,T,10]
{
    const int b   = blockIdx.x;
    const int tid = threadIdx.x;
    const int g   = tid >> 7;        // 0..3  (wave-uniform)
    const int l   = tid & 127;       // 0..127
    const int kbase = 32 * g;
    const int cbase = 4 * l;

    __shared__ __align__(16) float wx1L[4 * LROWS * G4];  // 128 KB
    __shared__ __align__(16) float h0s[U];
    __shared__ __align__(16) float h1s[U];
    __shared__ __align__(16) float hns[U];
    __shared__ __align__(16) float zs4[4 * G4];           // split-K partials
    __shared__ float WfcL[U * NC];
    __shared__ float bfcL[NC];
    __shared__ float psum[2], psq[2];                     // LN moments per half

    // ---- register-cached Wh0 slice (loop-invariant, 128 VGPRs) ----
    float4 wh0c[32];
    #pragma unroll
    for (int kk = 0; kk < 32; ++kk)
        wh0c[kk] = *reinterpret_cast<const float4*>(&Wh0[(kbase + kk) * G4 + cbase]);

    // ---- LDS-cached Wx1 rows [32g .. 32g+15] for each g (one-time, coalesced)
    for (int i = tid; i < 4 * LROWS * (G4 / 4); i += 512) {  // i = float4 index
        const int row = i >> 7;          // 0..63 (128 float4 per row)
        const int c4  = i & 127;
        const int gb  = row >> 4;        // K-group
        const int r   = row & (LROWS - 1);
        *reinterpret_cast<float4*>(&wx1L[row * G4 + 4 * c4]) =
            *reinterpret_cast<const float4*>(&Wx1[(gb * 32 + r) * G4 + 4 * c4]);
    }

    // g==0 threads fold bias + x@Wx0 into their partial (wave-uniform branch)
    float4 b0v = {0,0,0,0}, b1v = {0,0,0,0};
    float4 wx0a = {0,0,0,0}, wx0b = {0,0,0,0}, wx0c = {0,0,0,0};
    if (g == 0) {
        b0v  = *reinterpret_cast<const float4*>(&b0[cbase]);
        b1v  = *reinterpret_cast<const float4*>(&b1[cbase]);
        wx0a = *reinterpret_cast<const float4*>(&Wx0[cbase]);
        wx0b = *reinterpret_cast<const float4*>(&Wx0[G4 + cbase]);
        wx0c = *reinterpret_cast<const float4*>(&Wx0[2 * G4 + cbase]);
    }

    // per-unit state in registers (tid<128 owns unit tid)
    float tau0r = 0.f, s0r = 0.f, tau1r = 0.f, s1r = 0.f, gr = 0.f, br = 0.f;
    float c0r = 0.f, c1r = 0.f, h0r = 0.f, h1r = 0.f;
    if (tid < U) {
        tau0r = tau0[tid]; s0r = s0[tid];
        tau1r = tau1[tid]; s1r = s1[tid];
        gr = gamma_[tid];  br = beta_[tid];
        h0s[tid] = 0.0f;   h1s[tid] = 0.0f;
    }
    for (int i = tid; i < U * NC; i += 512) WfcL[i] = Wfc[i];
    if (tid < NC) bfcL[tid] = bfc[tid];
    __syncthreads();

    const float* xp = inputs + (size_t)b * TSTEPS * 3;
    const float* tp = times  + (size_t)b * TSTEPS;
    float*       op = out    + (size_t)b * TSTEPS * NC;
    const float* wx1p = Wx1 + kbase * G4 + cbase;   // streamed rows 16..31
    const float* wh1p = Wh1 + kbase * G4 + cbase;   // streamed rows 0..31
    const float* wx1l = wx1L + (g * LROWS) * G4 + cbase;

    for (int t = 0; t < TSTEPS; ++t) {
        const float x0 = xp[3 * t + 0];
        const float x1 = xp[3 * t + 1];
        const float x2 = xp[3 * t + 2];
        const float tv = tp[t];

        // ---- phase 1: layer-0 partial (registers + LDS broadcast only)
        float4 acc = {0,0,0,0};
        if (g == 0) {
            acc = b0v;
            acc = f4ma(x0, wx0a, acc);
            acc = f4ma(x1, wx0b, acc);
            acc = f4ma(x2, wx0c, acc);
        }
        #pragma unroll
        for (int q = 0; q < 8; ++q) {
            const float4 h4 = *reinterpret_cast<const float4*>(&h0s[kbase + 4 * q]);
            acc = f4ma(h4.x, wh0c[4 * q + 0], acc);
            acc = f4ma(h4.y, wh0c[4 * q + 1], acc);
            acc = f4ma(h4.z, wh0c[4 * q + 2], acc);
            acc = f4ma(h4.w, wh0c[4 * q + 3], acc);
        }
        *reinterpret_cast<float4*>(&zs4[g * G4 + cbase]) = acc;
        __syncthreads();                                            // bar 1

        // ---- phase 2: layer-0 gates + state + LN one-pass moments (tid<128)
        if (tid < U) {
            float zi = 0.f, zf = 0.f, zg = 0.f, zo = 0.f;
            #pragma unroll
            for (int gg2 = 0; gg2 < 4; ++gg2) {
                zi += zs4[gg2 * G4 + tid];
                zf += zs4[gg2 * G4 + tid + U];
                zg += zs4[gg2 * G4 + tid + 2 * U];
                zo += zs4[gg2 * G4 + tid + 3 * U];
            }
            const float ig = sigm(zi);
            const float fg = sigm(zf);
            const float gv = tanhf(zg);
            const float og = sigm(zo);
            const float ch = fg * c0r + ig * gv;
            const float hh = og * tanhf(ch);
            const float k  = tgate(tv, tau0r, s0r);
            h0r = k * hh + (1.0f - k) * h0r;
            c0r = k * ch + (1.0f - k) * c0r;
            h0s[tid] = h0r;
            float ssum = h0r;
            float qsum = h0r * h0r;
            #pragma unroll
            for (int off = 1; off < 64; off <<= 1) {
                ssum += __shfl_xor(ssum, off);
                qsum += __shfl_xor(qsum, off);
            }
            if ((tid & 63) == 0) {
                psum[tid >> 6] = ssum;
                psq[tid >> 6]  = qsum;
            }
        }
        __syncthreads();                                            // bar 2

        // ---- phase 3: LayerNorm apply (tid<128)
        if (tid < U) {
            const float s_  = psum[0] + psum[1];
            const float q_  = psq[0] + psq[1];
            const float mu  = s_ * (1.0f / 128.0f);
            const float var = q_ * (1.0f / 128.0f) - mu * mu;
            const float rstd = rsqrtf(var + 1e-3f);
            hns[tid] = gr * (h0r - mu) * rstd + br;
        }
        __syncthreads();                                            // bar 3

        // ---- phase 4: layer-1 partial: hn@Wx1 + h1@Wh1 over K-quarter
        //      Wx1 rows 0..15 from LDS cache; rows 16..31 + Wh1 from L2.
        float4 acc1 = {0,0,0,0};
        if (g == 0) acc1 = b1v;
        #pragma unroll
        for (int q = 0; q < 8; ++q) {
            const float4 hn4 = *reinterpret_cast<const float4*>(&hns[kbase + 4 * q]);
            const float4 h14 = *reinterpret_cast<const float4*>(&h1s[kbase + 4 * q]);
            #pragma unroll
            for (int i = 0; i < 4; ++i) {
                const int kk = 4 * q + i;
                const float4 wh = *reinterpret_cast<const float4*>(&wh1p[kk * G4]);
                float4 wx;
                if (kk < LROWS) wx = *reinterpret_cast<const float4*>(&wx1l[kk * G4]);
                else            wx = *reinterpret_cast<const float4*>(&wx1p[kk * G4]);
                const float hnv = (i == 0) ? hn4.x : (i == 1) ? hn4.y : (i == 2) ? hn4.z : hn4.w;
                const float h1v = (i == 0) ? h14.x : (i == 1) ? h14.y : (i == 2) ? h14.z : h14.w;
                acc1 = f4ma(hnv, wx, acc1);
                acc1 = f4ma(h1v, wh, acc1);
            }
        }
        *reinterpret_cast<float4*>(&zs4[g * G4 + cbase]) = acc1;
        __syncthreads();                                            // bar 4

        // ---- phase 5: layer-1 gates + state update (tid<128)
        if (tid < U) {
            float zi = 0.f, zf = 0.f, zg = 0.f, zo = 0.f;
            #pragma unroll
            for (int gg2 = 0; gg2 < 4; ++gg2) {
                zi += zs4[gg2 * G4 + tid];
                zf += zs4[gg2 * G4 + tid + U];
                zg += zs4[gg2 * G4 + tid + 2 * U];
                zo += zs4[gg2 * G4 + tid + 3 * U];
            }
            const float ig = sigm(zi);
            const float fg = sigm(zf);
            const float gv = tanhf(zg);
            const float og = sigm(zo);
            const float ch = fg * c1r + ig * gv;
            const float hh = og * tanhf(ch);
            const float k  = tgate(tv, tau1r, s1r);
            h1r = k * hh + (1.0f - k) * h1r;
            c1r = k * ch + (1.0f - k) * c1r;
            h1s[tid] = h1r;
        }
        __syncthreads();                                            // bar 5

        // ---- phase 6: FC + softmax (wave 0 only)
        // h1s rewrite can't happen until next step's bar4, after wave0 passes
        // next bar1 — so reading h1s here without a trailing barrier is safe.
        if (tid < 64) {
            const float a  = h1s[tid];
            const float bv = h1s[tid + 64];
            float p[NC];
            #pragma unroll
            for (int c = 0; c < NC; ++c)
                p[c] = a * WfcL[tid * NC + c] + bv * WfcL[(tid + 64) * NC + c];
            #pragma unroll
            for (int off = 1; off < 64; off <<= 1) {
                #pragma unroll
                for (int c = 0; c < NC; ++c) p[c] += __shfl_xor(p[c], off);
            }
            float m = -1e30f;
            #pragma unroll
            for (int c = 0; c < NC; ++c) { p[c] += bfcL[c]; m = fmaxf(m, p[c]); }
            float ss = 0.0f;
            #pragma unroll
            for (int c = 0; c < NC; ++c) { p[c] = __expf(p[c] - m); ss += p[c]; }
            const float inv = 1.0f / ss;
            if (tid < NC) op[t * NC + tid] = p[tid] * inv;
        }
    }
}

extern "C" void kernel_launch(void* const* d_in, const int* in_sizes, int n_in,
                              void* d_out, int out_size, void* d_ws, size_t ws_size,
                              hipStream_t stream) {
    const float* inputs = (const float*)d_in[0];
    const float* times  = (const float*)d_in[1];
    const float* Wx0    = (const float*)d_in[2];
    const float* Wh0    = (const float*)d_in[3];
    const float* b0     = (const float*)d_in[4];
    const float* tau0   = (const float*)d_in[5];
    const float* s0     = (const float*)d_in[6];
    const float* Wx1    = (const float*)d_in[7];
    const float* Wh1    = (const float*)d_in[8];
    const float* b1     = (const float*)d_in[9];
    const float* tau1   = (const float*)d_in[10];
    const float* s1     = (const float*)d_in[11];
    const float* gamma_ = (const float*)d_in[12];
    const float* beta_  = (const float*)d_in[13];
    const float* Wfc    = (const float*)d_in[14];
    const float* bfc    = (const float*)d_in[15];
    float* out = (float*)d_out;

    dim3 grid(BATCH);
    dim3 block(512);
    hipLaunchKernelGGL(plstm_fused, grid, block, 0, stream,
                       inputs, times, Wx0, Wh0, b0, tau0, s0,
                       Wx1, Wh1, b1, tau1, s1, gamma_, beta_, Wfc, bfc, out);
}

// Round 5
// 15954.845 us; speedup vs baseline: 1.2305x; 1.0049x over previous
//
#include <hip/hip_runtime.h>
#include <math.h>

// Problem constants (fixed by setup_inputs)
constexpr int U      = 128;   // UNITS
constexpr int G4     = 512;   // 4*U gate width
constexpr int NC     = 10;    // classes
constexpr int TSTEPS = 1000;
constexpr int BATCH  = 256;

// LDS-cached rows per K-group (of 32) for each matrix. 4*(C0+C1+C2) rows
// * 2 KB/row = 136 KB of LDS weight cache; total LDS 150.6 KB < 160 KB.
constexpr int C0 = 6;   // Wh0
constexpr int C1 = 6;   // Wx1
constexpr int C2 = 5;   // Wh1

__device__ __forceinline__ float sigm(float x) {
    return 1.0f / (1.0f + __expf(-x));
}

// matches jnp.mod (floor-mod) semantics: fmod exact, then sign-adjust
__device__ __forceinline__ float tgate(float t, float tau, float s) {
    float r = fmodf(t - s, tau);
    if (r < 0.0f) r += tau;
    float phi = r / tau;
    if (phi < 0.025f) return 40.0f * phi;        // 2*phi/R_ON
    if (phi < 0.05f)  return 2.0f - 40.0f * phi; // 2 - 2*phi/R_ON
    return 0.001f * phi;                          // ALPHA*phi
}

__device__ __forceinline__ float4 f4ma(float s, float4 a, float4 acc) {
    acc.x += s * a.x; acc.y += s * a.y; acc.z += s * a.z; acc.w += s * a.w;
    return acc;
}

// One workgroup per batch element, 512 threads = 8 waves, 1 block/CU.
// Thread tid: g = tid>>7 (K-quarter, wave-uniform), l = tid&127,
// owns output columns 4l..4l+3 and K-range [32g, 32g+32).
//
// Round 2/3/4 lesson: ANY >128-VGPR loop-carried weight cache gets spilled to
// scratch by the allocator (hints ignored) and the kernel becomes HBM-bound on
// scratch traffic. This version is allocator-proof: NO register-resident
// weights (live set ~70 VGPRs), LDS holds 136 KB of weights (cannot spill),
// the rest streams from L2 as coalesced dwordx4 (weights are block-shared and
// fully L2-resident).
__global__ __launch_bounds__(512) void plstm_fused(
    const float* __restrict__ inputs,  // [B,T,3]
    const float* __restrict__ times,   // [B,T]
    const float* __restrict__ Wx0,     // [3,512]
    const float* __restrict__ Wh0,     // [128,512]
    const float* __restrict__ b0,      // [512]
    const float* __restrict__ tau0,    // [128]
    const float* __restrict__ s0,      // [128]
    const float* __restrict__ Wx1,     // [128,512]
    const float* __restrict__ Wh1,     // [128,512]
    const float* __restrict__ b1,      // [512]
    const float* __restrict__ tau1,    // [128]
    const float* __restrict__ s1,      // [128]
    const float* __restrict__ gamma_,  // [128]
    const float* __restrict__ beta_,   // [128]
    const float* __restrict__ Wfc,     // [128,10]
    const float* __restrict__ bfc,     // [10]
    float* __restrict__ out)           // [B,T,10]
{
    const int b   = blockIdx.x;
    const int tid = threadIdx.x;
    const int g   = tid >> 7;        // 0..3  (wave-uniform)
    const int l   = tid & 127;       // 0..127
    const int kbase = 32 * g;
    const int cbase = 4 * l;

    __shared__ __align__(16) float wh0L[4 * C0 * G4];   // 48 KB
    __shared__ __align__(16) float wx1L[4 * C1 * G4];   // 48 KB
    __shared__ __align__(16) float wh1L[4 * C2 * G4];   // 40 KB
    __shared__ __align__(16) float zs4[4 * G4];         // split-K partials, 8 KB
    __shared__ __align__(16) float h0s[U];
    __shared__ __align__(16) float h1s[U];
    __shared__ __align__(16) float hns[U];
    __shared__ float WfcL[U * NC];
    __shared__ float bfcL[NC];
    __shared__ float psum[2], psq[2];                   // LN moments per half

    // ---- one-time LDS staging of the cached weight rows (coalesced float4)
    {
        // rows [32*gb .. 32*gb + C) of W -> dst[(gb*C + r)*G4 + col]
        const float4* Wh0v = reinterpret_cast<const float4*>(Wh0);
        const float4* Wx1v = reinterpret_cast<const float4*>(Wx1);
        const float4* Wh1v = reinterpret_cast<const float4*>(Wh1);
        float4* d0 = reinterpret_cast<float4*>(wh0L);
        float4* d1 = reinterpret_cast<float4*>(wx1L);
        float4* d2 = reinterpret_cast<float4*>(wh1L);
        for (int i = tid; i < 4 * C0 * 128; i += 512) {
            const int row = i >> 7, c4 = i & 127;
            d0[row * 128 + c4] = Wh0v[((row / C0) * 32 + (row % C0)) * 128 + c4];
        }
        for (int i = tid; i < 4 * C1 * 128; i += 512) {
            const int row = i >> 7, c4 = i & 127;
            d1[row * 128 + c4] = Wx1v[((row / C1) * 32 + (row % C1)) * 128 + c4];
        }
        for (int i = tid; i < 4 * C2 * 128; i += 512) {
            const int row = i >> 7, c4 = i & 127;
            d2[row * 128 + c4] = Wh1v[((row / C2) * 32 + (row % C2)) * 128 + c4];
        }
    }

    // g==0 threads fold bias + x@Wx0 into their partial (wave-uniform branch)
    float4 b0v = {0,0,0,0}, b1v = {0,0,0,0};
    float4 wx0a = {0,0,0,0}, wx0b = {0,0,0,0}, wx0c = {0,0,0,0};
    if (g == 0) {
        b0v  = *reinterpret_cast<const float4*>(&b0[cbase]);
        b1v  = *reinterpret_cast<const float4*>(&b1[cbase]);
        wx0a = *reinterpret_cast<const float4*>(&Wx0[cbase]);
        wx0b = *reinterpret_cast<const float4*>(&Wx0[G4 + cbase]);
        wx0c = *reinterpret_cast<const float4*>(&Wx0[2 * G4 + cbase]);
    }

    // per-unit state in registers (tid<128 owns unit tid)
    float tau0r = 0.f, s0r = 0.f, tau1r = 0.f, s1r = 0.f, gr = 0.f, br = 0.f;
    float c0r = 0.f, c1r = 0.f, h0r = 0.f, h1r = 0.f;
    if (tid < U) {
        tau0r = tau0[tid]; s0r = s0[tid];
        tau1r = tau1[tid]; s1r = s1[tid];
        gr = gamma_[tid];  br = beta_[tid];
        h0s[tid] = 0.0f;   h1s[tid] = 0.0f;
    }
    for (int i = tid; i < U * NC; i += 512) WfcL[i] = Wfc[i];
    if (tid < NC) bfcL[tid] = bfc[tid];
    __syncthreads();

    const float* xp = inputs + (size_t)b * TSTEPS * 3;
    const float* tp = times  + (size_t)b * TSTEPS;
    float*       op = out    + (size_t)b * TSTEPS * NC;

    // per-thread streaming/cache base pointers (loop-invariant)
    const float* wh0p = Wh0 + kbase * G4 + cbase;
    const float* wx1p = Wx1 + kbase * G4 + cbase;
    const float* wh1p = Wh1 + kbase * G4 + cbase;
    const float* wh0l = wh0L + (g * C0) * G4 + cbase;
    const float* wx1l = wx1L + (g * C1) * G4 + cbase;
    const float* wh1l = wh1L + (g * C2) * G4 + cbase;

    for (int t = 0; t < TSTEPS; ++t) {
        const float x0 = xp[3 * t + 0];
        const float x1 = xp[3 * t + 1];
        const float x2 = xp[3 * t + 2];
        const float tv = tp[t];

        // ---- phase 1: layer-0 partial; Wh0 rows 0..C0-1 from LDS, rest from L2
        float4 acc = {0,0,0,0};
        if (g == 0) {
            acc = b0v;
            acc = f4ma(x0, wx0a, acc);
            acc = f4ma(x1, wx0b, acc);
            acc = f4ma(x2, wx0c, acc);
        }
        #pragma unroll
        for (int q = 0; q < 8; ++q) {
            const float4 h4 = *reinterpret_cast<const float4*>(&h0s[kbase + 4 * q]);
            #pragma unroll
            for (int i = 0; i < 4; ++i) {
                const int kk = 4 * q + i;
                float4 w;
                if (kk < C0) w = *reinterpret_cast<const float4*>(&wh0l[kk * G4]);
                else         w = *reinterpret_cast<const float4*>(&wh0p[kk * G4]);
                const float hv = (i == 0) ? h4.x : (i == 1) ? h4.y : (i == 2) ? h4.z : h4.w;
                acc = f4ma(hv, w, acc);
            }
        }
        *reinterpret_cast<float4*>(&zs4[g * G4 + cbase]) = acc;
        __syncthreads();                                            // bar 1

        // ---- phase 2: layer-0 gates + state + LN one-pass moments (tid<128)
        if (tid < U) {
            float zi = 0.f, zf = 0.f, zg = 0.f, zo = 0.f;
            #pragma unroll
            for (int gg2 = 0; gg2 < 4; ++gg2) {
                zi += zs4[gg2 * G4 + tid];
                zf += zs4[gg2 * G4 + tid + U];
                zg += zs4[gg2 * G4 + tid + 2 * U];
                zo += zs4[gg2 * G4 + tid + 3 * U];
            }
            const float ig = sigm(zi);
            const float fg = sigm(zf);
            const float gv = tanhf(zg);
            const float og = sigm(zo);
            const float ch = fg * c0r + ig * gv;
            const float hh = og * tanhf(ch);
            const float k  = tgate(tv, tau0r, s0r);
            h0r = k * hh + (1.0f - k) * h0r;
            c0r = k * ch + (1.0f - k) * c0r;
            h0s[tid] = h0r;
            float ssum = h0r;
            float qsum = h0r * h0r;
            #pragma unroll
            for (int off = 1; off < 64; off <<= 1) {
                ssum += __shfl_xor(ssum, off);
                qsum += __shfl_xor(qsum, off);
            }
            if ((tid & 63) == 0) {
                psum[tid >> 6] = ssum;
                psq[tid >> 6]  = qsum;
            }
        }
        __syncthreads();                                            // bar 2

        // ---- phase 3: LayerNorm apply (tid<128)
        if (tid < U) {
            const float s_  = psum[0] + psum[1];
            const float q_  = psq[0] + psq[1];
            const float mu  = s_ * (1.0f / 128.0f);
            const float var = q_ * (1.0f / 128.0f) - mu * mu;
            const float rstd = rsqrtf(var + 1e-3f);
            hns[tid] = gr * (h0r - mu) * rstd + br;
        }
        __syncthreads();                                            // bar 3

        // ---- phase 4: layer-1 partial; Wx1/Wh1 cached rows from LDS, rest L2
        float4 acc1 = {0,0,0,0};
        if (g == 0) acc1 = b1v;
        #pragma unroll
        for (int q = 0; q < 8; ++q) {
            const float4 hn4 = *reinterpret_cast<const float4*>(&hns[kbase + 4 * q]);
            const float4 h14 = *reinterpret_cast<const float4*>(&h1s[kbase + 4 * q]);
            #pragma unroll
            for (int i = 0; i < 4; ++i) {
                const int kk = 4 * q + i;
                float4 wx, wh;
                if (kk < C1) wx = *reinterpret_cast<const float4*>(&wx1l[kk * G4]);
                else         wx = *reinterpret_cast<const float4*>(&wx1p[kk * G4]);
                if (kk < C2) wh = *reinterpret_cast<const float4*>(&wh1l[kk * G4]);
                else         wh = *reinterpret_cast<const float4*>(&wh1p[kk * G4]);
                const float hnv = (i == 0) ? hn4.x : (i == 1) ? hn4.y : (i == 2) ? hn4.z : hn4.w;
                const float h1v = (i == 0) ? h14.x : (i == 1) ? h14.y : (i == 2) ? h14.z : h14.w;
                acc1 = f4ma(hnv, wx, acc1);
                acc1 = f4ma(h1v, wh, acc1);
            }
        }
        *reinterpret_cast<float4*>(&zs4[g * G4 + cbase]) = acc1;
        __syncthreads();                                            // bar 4

        // ---- phase 5: layer-1 gates + state update (tid<128)
        if (tid < U) {
            float zi = 0.f, zf = 0.f, zg = 0.f, zo = 0.f;
            #pragma unroll
            for (int gg2 = 0; gg2 < 4; ++gg2) {
                zi += zs4[gg2 * G4 + tid];
                zf += zs4[gg2 * G4 + tid + U];
                zg += zs4[gg2 * G4 + tid + 2 * U];
                zo += zs4[gg2 * G4 + tid + 3 * U];
            }
            const float ig = sigm(zi);
            const float fg = sigm(zf);
            const float gv = tanhf(zg);
            const float og = sigm(zo);
            const float ch = fg * c1r + ig * gv;
            const float hh = og * tanhf(ch);
            const float k  = tgate(tv, tau1r, s1r);
            h1r = k * hh + (1.0f - k) * h1r;
            c1r = k * ch + (1.0f - k) * c1r;
            h1s[tid] = h1r;
        }
        __syncthreads();                                            // bar 5

        // ---- phase 6: FC + softmax (wave 0 only)
        // h1s is next rewritten in next step's phase 5 (after next bar4, which
        // wave 0 must also reach) — safe to read here without a trailing bar.
        if (tid < 64) {
            const float a  = h1s[tid];
            const float bv = h1s[tid + 64];
            float p[NC];
            #pragma unroll
            for (int c = 0; c < NC; ++c)
                p[c] = a * WfcL[tid * NC + c] + bv * WfcL[(tid + 64) * NC + c];
            #pragma unroll
            for (int off = 1; off < 64; off <<= 1) {
                #pragma unroll
                for (int c = 0; c < NC; ++c) p[c] += __shfl_xor(p[c], off);
            }
            float m = -1e30f;
            #pragma unroll
            for (int c = 0; c < NC; ++c) { p[c] += bfcL[c]; m = fmaxf(m, p[c]); }
            float ss = 0.0f;
            #pragma unroll
            for (int c = 0; c < NC; ++c) { p[c] = __expf(p[c] - m); ss += p[c]; }
            const float inv = 1.0f / ss;
            if (tid < NC) op[t * NC + tid] = p[tid] * inv;
        }
    }
}

extern "C" void kernel_launch(void* const* d_in, const int* in_sizes, int n_in,
                              void* d_out, int out_size, void* d_ws, size_t ws_size,
                              hipStream_t stream) {
    const float* inputs = (const float*)d_in[0];
    const float* times  = (const float*)d_in[1];
    const float* Wx0    = (const float*)d_in[2];
    const float* Wh0    = (const float*)d_in[3];
    const float* b0     = (const float*)d_in[4];
    const float* tau0   = (const float*)d_in[5];
    const float* s0     = (const float*)d_in[6];
    const float* Wx1    = (const float*)d_in[7];
    const float* Wh1    = (const float*)d_in[8];
    const float* b1     = (const float*)d_in[9];
    const float* tau1   = (const float*)d_in[10];
    const float* s1     = (const float*)d_in[11];
    const float* gamma_ = (const float*)d_in[12];
    const float* beta_  = (const float*)d_in[13];
    const float* Wfc    = (const float*)d_in[14];
    const float* bfc    = (const float*)d_in[15];
    float* out = (float*)d_out;

    dim3 grid(BATCH);
    dim3 block(512);
    hipLaunchKernelGGL(plstm_fused, grid, block, 0, stream,
                       inputs, times, Wx0, Wh0, b0, tau0, s0,
                       Wx1, Wh1, b1, tau1, s1, gamma_, beta_, Wfc, bfc, out);
}